// Round 1
// baseline (390.796 us; speedup 1.0000x reference)
//
#include <hip/hip_runtime.h>

// ---------------------------------------------------------------------------
// Types
// ---------------------------------------------------------------------------
using bf16x8 = __attribute__((ext_vector_type(8))) __bf16;
using f32x4  = __attribute__((ext_vector_type(4))) float;

__device__ __forceinline__ unsigned short f2bf(float f) {
    unsigned int u = __float_as_uint(f);
    unsigned int r = (u + 0x7FFFu + ((u >> 16) & 1u)) >> 16;
    return (unsigned short)r;
}

// ---------------------------------------------------------------------------
// fp32 -> bf16 convert (weights)
// ---------------------------------------------------------------------------
__global__ __launch_bounds__(256) void cvt_kernel(const float* __restrict__ in,
                                                  unsigned short* __restrict__ out,
                                                  int n) {
    int i = (blockIdx.x * 256 + threadIdx.x) * 4;
    if (i < n) {
        float4 v = *(const float4*)(in + i);
        unsigned short o0 = f2bf(v.x), o1 = f2bf(v.y), o2 = f2bf(v.z), o3 = f2bf(v.w);
        ushort4 o = make_ushort4(o0, o1, o2, o3);
        *(ushort4*)(out + i) = o;
    }
}

// ---------------------------------------------------------------------------
// LayerNorm: one 1024-wide row per block (256 threads x 4 elems), bf16 out
// ---------------------------------------------------------------------------
__global__ __launch_bounds__(256) void ln_kernel(const float* __restrict__ in,
                                                 const float* __restrict__ w,
                                                 const float* __restrict__ b,
                                                 unsigned short* __restrict__ out) {
    const int row = blockIdx.x;
    const int tid = threadIdx.x;
    const float4 v = *(const float4*)(in + (size_t)row * 1024 + tid * 4);
    float s  = v.x + v.y + v.z + v.w;
    float ss = v.x * v.x + v.y * v.y + v.z * v.z + v.w * v.w;
    #pragma unroll
    for (int m = 1; m < 64; m <<= 1) {
        s  += __shfl_xor(s, m, 64);
        ss += __shfl_xor(ss, m, 64);
    }
    __shared__ float red[8];
    if ((tid & 63) == 0) { red[(tid >> 6) * 2] = s; red[(tid >> 6) * 2 + 1] = ss; }
    __syncthreads();
    s  = red[0] + red[2] + red[4] + red[6];
    ss = red[1] + red[3] + red[5] + red[7];
    const float mu  = s * (1.0f / 1024.0f);
    const float var = ss * (1.0f / 1024.0f) - mu * mu;
    const float rstd = rsqrtf(var + 1e-5f);
    const float4 wv = *(const float4*)(w + tid * 4);
    const float4 bv = *(const float4*)(b + tid * 4);
    ushort4 o;
    o.x = f2bf((v.x - mu) * rstd * wv.x + bv.x);
    o.y = f2bf((v.y - mu) * rstd * wv.y + bv.y);
    o.z = f2bf((v.z - mu) * rstd * wv.z + bv.z);
    o.w = f2bf((v.w - mu) * rstd * wv.w + bv.w);
    *(ushort4*)(out + (size_t)row * 1024 + tid * 4) = o;
}

// ---------------------------------------------------------------------------
// GEMM: C[M,N] = A[M,K](bf16) @ W[N,K]^T(bf16) + bias, templated epilogue.
// 128x128 tile, 4 waves (each 64x64), 16x16x32 bf16 MFMA, BK=32,
// global_load_lds width-16 staging (m97 structure).
// EPI: 0=QK mix, 1=V mix+transpose, 2=out-proj+resid, 3=GELU->bf16, 4=mlp2+resid
// ---------------------------------------------------------------------------
template <int EPI>
__global__ __launch_bounds__(256, 2)
void gemm_bt(const unsigned short* __restrict__ A,
             const unsigned short* __restrict__ W,
             const float* __restrict__ bias,
             int M, int N, int K,
             const float* __restrict__ e0, const float* __restrict__ e1,
             float* __restrict__ o0, float* __restrict__ o1,
             unsigned short* __restrict__ u0, unsigned short* __restrict__ u1) {
    __shared__ unsigned short As[128 * 32];
    __shared__ unsigned short Bs[128 * 32];
    const int tid  = threadIdx.x;
    const int wave = tid >> 6, lane = tid & 63;
    const int wr = wave >> 1, wc = wave & 1;
    const int gm0 = blockIdx.y * 128, gn0 = blockIdx.x * 128;

    f32x4 acc[4][4] = {};

    const int srow  = lane >> 2;        // row within 16-row chunk
    const int skoff = (lane & 3) * 8;   // k element offset

    for (int k0 = 0; k0 < K; k0 += 32) {
        #pragma unroll
        for (int i = 0; i < 2; ++i) {
            const int c = wave * 2 + i;
            const unsigned short* ga = A + (size_t)(gm0 + c * 16 + srow) * K + (k0 + skoff);
            const unsigned short* gb = W + (size_t)(gn0 + c * 16 + srow) * K + (k0 + skoff);
            __builtin_amdgcn_global_load_lds(
                (const __attribute__((address_space(1))) void*)ga,
                (__attribute__((address_space(3))) void*)((char*)As + c * 1024), 16, 0, 0);
            __builtin_amdgcn_global_load_lds(
                (const __attribute__((address_space(1))) void*)gb,
                (__attribute__((address_space(3))) void*)((char*)Bs + c * 1024), 16, 0, 0);
        }
        __syncthreads();
        bf16x8 af[4], bfr[4];
        #pragma unroll
        for (int m = 0; m < 4; ++m)
            af[m] = *(const bf16x8*)&As[(wr * 64 + m * 16 + (lane & 15)) * 32 + (lane >> 4) * 8];
        #pragma unroll
        for (int n = 0; n < 4; ++n)
            bfr[n] = *(const bf16x8*)&Bs[(wc * 64 + n * 16 + (lane & 15)) * 32 + (lane >> 4) * 8];
        #pragma unroll
        for (int m = 0; m < 4; ++m)
            #pragma unroll
            for (int n = 0; n < 4; ++n)
                acc[m][n] = __builtin_amdgcn_mfma_f32_16x16x32_bf16(af[m], bfr[n], acc[m][n], 0, 0, 0);
        __syncthreads();
    }

    // epilogue
    #pragma unroll
    for (int m = 0; m < 4; ++m)
    #pragma unroll
    for (int n = 0; n < 4; ++n)
    #pragma unroll
    for (int j = 0; j < 4; ++j) {
        const int r = gm0 + wr * 64 + m * 16 + (lane >> 4) * 4 + j;
        const int c = gn0 + wc * 64 + n * 16 + (lane & 15);
        const float val = acc[m][n][j] + bias[c];
        if constexpr (EPI == 0) {            // qk: mix with Query/Key inputs
            const int bb = r >> 10, nn = r & 1023;
            const int h = c >> 7, hs = (c >> 1) & 63, isk = c & 1;
            const size_t idx = (((size_t)(bb * 16 + h)) * 1024 + nn) * 64 + hs;
            if (!isk) { const float mx = 0.7f * val + 0.3f * e0[idx]; o0[idx] = mx; u0[idx] = f2bf(mx); }
            else      { const float mx = 0.7f * val + 0.3f * e1[idx]; o1[idx] = mx; u1[idx] = f2bf(mx); }
        } else if constexpr (EPI == 1) {     // v: mix + write transposed bf16
            const int bb = r >> 10, nn = r & 1023;
            const int h = c >> 6, hs = c & 63;
            const size_t idx = (((size_t)(bb * 16 + h)) * 1024 + nn) * 64 + hs;
            const float mx = 0.7f * val + 0.3f * e0[idx];
            o0[idx] = mx;
            u0[(((size_t)(bb * 16 + h)) * 64 + hs) * 1024 + nn] = f2bf(mx);
        } else if constexpr (EPI == 2) {     // out-proj + residual -> fp32 y1
            const size_t idx = (size_t)r * N + c;
            o0[idx] = val + e0[idx];
        } else if constexpr (EPI == 3) {     // GELU (exact, erf) -> bf16
            const float g = 0.5f * val * (1.0f + erff(val * 0.70710678118f));
            u0[(size_t)r * N + c] = f2bf(g);
        } else {                             // mlp2 + residual -> fp32 out
            const size_t idx = (size_t)r * N + c;
            o0[idx] = val + e0[idx];
        }
    }
}

// ---------------------------------------------------------------------------
// Flash attention: grid (N/64, B*H), 256 threads (4 waves x 16 q-rows).
// Qb,Kb: (B*H, N, 64) bf16.  Vt: (B*H, 64, N) bf16.  Ob: (B*N, 1024) bf16.
// ---------------------------------------------------------------------------
__global__ __launch_bounds__(256, 2)
void attn_kernel(const unsigned short* __restrict__ Qb,
                 const unsigned short* __restrict__ Kb,
                 const unsigned short* __restrict__ Vt,
                 unsigned short* __restrict__ Ob) {
    const int bh = blockIdx.y;
    const int b = bh >> 4, h = bh & 15;
    const int tid = threadIdx.x, wave = tid >> 6, lane = tid & 63;
    const int qbase = blockIdx.x * 64 + wave * 16;

    const unsigned short* Qh = Qb + (size_t)bh * 1024 * 64;
    const unsigned short* Kh = Kb + (size_t)bh * 1024 * 64;
    const unsigned short* Vh = Vt + (size_t)bh * 64 * 1024;

    __shared__ unsigned short Ps[4][16][64];

    bf16x8 aq[2];
    {
        const int qr = qbase + (lane & 15);
        aq[0] = *(const bf16x8*)&Qh[(size_t)qr * 64 + 0  + (lane >> 4) * 8];
        aq[1] = *(const bf16x8*)&Qh[(size_t)qr * 64 + 32 + (lane >> 4) * 8];
    }

    f32x4 o[4] = {};
    float mrow[4] = {-1e30f, -1e30f, -1e30f, -1e30f};
    float lrow[4] = {0.f, 0.f, 0.f, 0.f};

    for (int t = 0; t < 16; ++t) {
        const int kb = t * 64;
        f32x4 s[4] = {};
        #pragma unroll
        for (int kt = 0; kt < 4; ++kt) {
            #pragma unroll
            for (int kk = 0; kk < 2; ++kk) {
                bf16x8 bk = *(const bf16x8*)&Kh[(size_t)(kb + kt * 16 + (lane & 15)) * 64 + kk * 32 + (lane >> 4) * 8];
                s[kt] = __builtin_amdgcn_mfma_f32_16x16x32_bf16(aq[kk], bk, s[kt], 0, 0, 0);
            }
            s[kt] *= 0.125f;  // 1/sqrt(64)
        }
        // per-row max over this kv tile (rows j, cols spread over 16 lanes)
        float pm[4];
        #pragma unroll
        for (int j = 0; j < 4; ++j) {
            float v = fmaxf(fmaxf(s[0][j], s[1][j]), fmaxf(s[2][j], s[3][j]));
            v = fmaxf(v, __shfl_xor(v, 1, 16));
            v = fmaxf(v, __shfl_xor(v, 2, 16));
            v = fmaxf(v, __shfl_xor(v, 4, 16));
            v = fmaxf(v, __shfl_xor(v, 8, 16));
            pm[j] = v;
        }
        float alpha[4], rs[4];
        #pragma unroll
        for (int j = 0; j < 4; ++j) {
            const float mnew = fmaxf(mrow[j], pm[j]);
            alpha[j] = __expf(mrow[j] - mnew);
            mrow[j] = mnew;
            rs[j] = 0.f;
        }
        #pragma unroll
        for (int kt = 0; kt < 4; ++kt)
            #pragma unroll
            for (int j = 0; j < 4; ++j) {
                const float p = __expf(s[kt][j] - mrow[j]);
                rs[j] += p;
                Ps[wave][(lane >> 4) * 4 + j][kt * 16 + (lane & 15)] = f2bf(p);
            }
        #pragma unroll
        for (int j = 0; j < 4; ++j) {
            float v = rs[j];
            v += __shfl_xor(v, 1, 16);
            v += __shfl_xor(v, 2, 16);
            v += __shfl_xor(v, 4, 16);
            v += __shfl_xor(v, 8, 16);
            lrow[j] = lrow[j] * alpha[j] + v;
        }
        #pragma unroll
        for (int dt = 0; dt < 4; ++dt)
            #pragma unroll
            for (int j = 0; j < 4; ++j)
                o[dt][j] *= alpha[j];
        __syncthreads();  // make P visible (write->read through LDS)
        #pragma unroll
        for (int kk = 0; kk < 2; ++kk) {
            bf16x8 pa = *(const bf16x8*)&Ps[wave][lane & 15][kk * 32 + (lane >> 4) * 8];
            #pragma unroll
            for (int dt = 0; dt < 4; ++dt) {
                bf16x8 vb = *(const bf16x8*)&Vh[(size_t)(dt * 16 + (lane & 15)) * 1024 + kb + kk * 32 + (lane >> 4) * 8];
                o[dt] = __builtin_amdgcn_mfma_f32_16x16x32_bf16(pa, vb, o[dt], 0, 0, 0);
            }
        }
        __syncthreads();  // protect P buffer before next iteration's writes
    }

    #pragma unroll
    for (int dt = 0; dt < 4; ++dt)
        #pragma unroll
        for (int j = 0; j < 4; ++j) {
            const int q = qbase + (lane >> 4) * 4 + j;
            const float val = o[dt][j] / lrow[j];
            Ob[((size_t)(b * 1024 + q)) * 1024 + h * 64 + dt * 16 + (lane & 15)] = f2bf(val);
        }
}

// ---------------------------------------------------------------------------
// Launch
// ---------------------------------------------------------------------------
extern "C" void kernel_launch(void* const* d_in, const int* in_sizes, int n_in,
                              void* d_out, int out_size, void* d_ws, size_t ws_size,
                              hipStream_t stream) {
    (void)in_sizes; (void)n_in; (void)out_size; (void)ws_size;
    const float* x     = (const float*)d_in[0];
    const float* Qin   = (const float*)d_in[1];
    const float* Kin   = (const float*)d_in[2];
    const float* Vin   = (const float*)d_in[3];
    const float* ln_w  = (const float*)d_in[4];
    const float* ln_b  = (const float*)d_in[5];
    const float* qk_w  = (const float*)d_in[6];
    const float* qk_b  = (const float*)d_in[7];
    const float* v_w   = (const float*)d_in[8];
    const float* v_b   = (const float*)d_in[9];
    const float* out_w = (const float*)d_in[10];
    const float* out_b = (const float*)d_in[11];
    const float* w1    = (const float*)d_in[12];
    const float* b1    = (const float*)d_in[13];
    const float* w2    = (const float*)d_in[14];
    const float* b2    = (const float*)d_in[15];

    const size_t FOUR_M = (size_t)4 * 1024 * 1024;
    float* out0 = (float*)d_out;
    float* Qout = out0 + FOUR_M;
    float* Kout = Qout + FOUR_M;
    float* Vout = Kout + FOUR_M;

    char* ws = (char*)d_ws;
    const size_t MB = 1024 * 1024;
    unsigned short* xn   = (unsigned short*)(ws + 0);        // 8MB (reused as xn2)
    unsigned short* qkwb = (unsigned short*)(ws + 8 * MB);   // 4MB
    unsigned short* vwb  = (unsigned short*)(ws + 12 * MB);  // 2MB
    unsigned short* owb  = (unsigned short*)(ws + 14 * MB);  // 2MB
    unsigned short* w1b  = (unsigned short*)(ws + 16 * MB);  // 8MB
    unsigned short* w2b  = (unsigned short*)(ws + 24 * MB);  // 8MB
    unsigned short* Qbuf = (unsigned short*)(ws + 32 * MB);  // 8MB
    unsigned short* Kbuf = (unsigned short*)(ws + 40 * MB);  // 8MB
    unsigned short* Vtb  = (unsigned short*)(ws + 48 * MB);  // 8MB
    unsigned short* atto = (unsigned short*)(ws + 56 * MB);  // 8MB
    unsigned short* hbuf = (unsigned short*)(ws + 32 * MB);  // 32MB, reuses Q/K/V/atto region
    float* y1 = (float*)(ws + 64 * MB);                      // 16MB

    // weight converts
    cvt_kernel<<<2048, 256, 0, stream>>>(qk_w, qkwb, 2048 * 1024);
    cvt_kernel<<<1024, 256, 0, stream>>>(v_w,  vwb,  1024 * 1024);
    cvt_kernel<<<1024, 256, 0, stream>>>(out_w, owb, 1024 * 1024);
    cvt_kernel<<<4096, 256, 0, stream>>>(w1, w1b, 4096 * 1024);
    cvt_kernel<<<4096, 256, 0, stream>>>(w2, w2b, 4096 * 1024);

    // LN1
    ln_kernel<<<4096, 256, 0, stream>>>(x, ln_w, ln_b, xn);

    // qk projection + mixing
    {
        dim3 g(2048 / 128, 4096 / 128);
        gemm_bt<0><<<g, 256, 0, stream>>>(xn, qkwb, qk_b, 4096, 2048, 1024,
                                          Qin, Kin, Qout, Kout, Qbuf, Kbuf);
    }
    // v projection + mixing (+ transposed bf16 copy)
    {
        dim3 g(1024 / 128, 4096 / 128);
        gemm_bt<1><<<g, 256, 0, stream>>>(xn, vwb, v_b, 4096, 1024, 1024,
                                          Vin, nullptr, Vout, nullptr, Vtb, nullptr);
    }
    // attention
    {
        dim3 g(16, 64);
        attn_kernel<<<g, 256, 0, stream>>>(Qbuf, Kbuf, Vtb, atto);
    }
    // out projection + residual -> y1
    {
        dim3 g(1024 / 128, 4096 / 128);
        gemm_bt<2><<<g, 256, 0, stream>>>(atto, owb, out_b, 4096, 1024, 1024,
                                          x, nullptr, y1, nullptr, nullptr, nullptr);
    }
    // LN2
    ln_kernel<<<4096, 256, 0, stream>>>(y1, ln_w, ln_b, xn);
    // MLP fc1 + GELU
    {
        dim3 g(4096 / 128, 4096 / 128);
        gemm_bt<3><<<g, 256, 0, stream>>>(xn, w1b, b1, 4096, 4096, 1024,
                                          nullptr, nullptr, nullptr, nullptr, hbuf, nullptr);
    }
    // MLP fc2 + residual -> out0
    {
        dim3 g(1024 / 128, 4096 / 128);
        gemm_bt<4><<<g, 256, 0, stream>>>(hbuf, w2b, b2, 4096, 1024, 4096,
                                          y1, nullptr, out0, nullptr, nullptr, nullptr);
    }
}

// Round 2
// 384.043 us; speedup vs baseline: 1.0176x; 1.0176x over previous
//
#include <hip/hip_runtime.h>

// ---------------------------------------------------------------------------
// Types
// ---------------------------------------------------------------------------
using bf16x8 = __attribute__((ext_vector_type(8))) __bf16;
using f32x4  = __attribute__((ext_vector_type(4))) float;

__device__ __forceinline__ unsigned short f2bf(float f) {
    unsigned int u = __float_as_uint(f);
    unsigned int r = (u + 0x7FFFu + ((u >> 16) & 1u)) >> 16;
    return (unsigned short)r;
}

// ---------------------------------------------------------------------------
// fp32 -> bf16 convert (weights)
// ---------------------------------------------------------------------------
__global__ __launch_bounds__(256) void cvt_kernel(const float* __restrict__ in,
                                                  unsigned short* __restrict__ out,
                                                  int n) {
    int i = (blockIdx.x * 256 + threadIdx.x) * 4;
    if (i < n) {
        float4 v = *(const float4*)(in + i);
        unsigned short o0 = f2bf(v.x), o1 = f2bf(v.y), o2 = f2bf(v.z), o3 = f2bf(v.w);
        ushort4 o = make_ushort4(o0, o1, o2, o3);
        *(ushort4*)(out + i) = o;
    }
}

// ---------------------------------------------------------------------------
// LayerNorm: one 1024-wide row per block (256 threads x 4 elems), bf16 out
// ---------------------------------------------------------------------------
__global__ __launch_bounds__(256) void ln_kernel(const float* __restrict__ in,
                                                 const float* __restrict__ w,
                                                 const float* __restrict__ b,
                                                 unsigned short* __restrict__ out) {
    const int row = blockIdx.x;
    const int tid = threadIdx.x;
    const float4 v = *(const float4*)(in + (size_t)row * 1024 + tid * 4);
    float s  = v.x + v.y + v.z + v.w;
    float ss = v.x * v.x + v.y * v.y + v.z * v.z + v.w * v.w;
    #pragma unroll
    for (int m = 1; m < 64; m <<= 1) {
        s  += __shfl_xor(s, m, 64);
        ss += __shfl_xor(ss, m, 64);
    }
    __shared__ float red[8];
    if ((tid & 63) == 0) { red[(tid >> 6) * 2] = s; red[(tid >> 6) * 2 + 1] = ss; }
    __syncthreads();
    s  = red[0] + red[2] + red[4] + red[6];
    ss = red[1] + red[3] + red[5] + red[7];
    const float mu  = s * (1.0f / 1024.0f);
    const float var = ss * (1.0f / 1024.0f) - mu * mu;
    const float rstd = rsqrtf(var + 1e-5f);
    const float4 wv = *(const float4*)(w + tid * 4);
    const float4 bv = *(const float4*)(b + tid * 4);
    ushort4 o;
    o.x = f2bf((v.x - mu) * rstd * wv.x + bv.x);
    o.y = f2bf((v.y - mu) * rstd * wv.y + bv.y);
    o.z = f2bf((v.z - mu) * rstd * wv.z + bv.z);
    o.w = f2bf((v.w - mu) * rstd * wv.w + bv.w);
    *(ushort4*)(out + (size_t)row * 1024 + tid * 4) = o;
}

// ---------------------------------------------------------------------------
// GEMM: C[M,N] = A[M,K](bf16) @ W[N,K]^T(bf16) + bias, templated epilogue.
// 128x128 tile, 4 waves (each 64x64), 16x16x32 bf16 MFMA, BK=32,
// global_load_lds width-16 staging (m97 structure).
// EPI: 0=QK mix, 1=V mix+transpose, 2=out-proj+resid, 3=GELU->bf16, 4=mlp2+resid
// ---------------------------------------------------------------------------
template <int EPI>
__global__ __launch_bounds__(256, 2)
void gemm_bt(const unsigned short* __restrict__ A,
             const unsigned short* __restrict__ W,
             const float* __restrict__ bias,
             int M, int N, int K,
             const float* __restrict__ e0, const float* __restrict__ e1,
             float* __restrict__ o0, float* __restrict__ o1,
             unsigned short* __restrict__ u0, unsigned short* __restrict__ u1) {
    __shared__ unsigned short As[128 * 32];
    __shared__ unsigned short Bs[128 * 32];
    const int tid  = threadIdx.x;
    const int wave = tid >> 6, lane = tid & 63;
    const int wr = wave >> 1, wc = wave & 1;
    const int gm0 = blockIdx.y * 128, gn0 = blockIdx.x * 128;

    f32x4 acc[4][4] = {};

    const int srow  = lane >> 2;        // row within 16-row chunk
    const int skoff = (lane & 3) * 8;   // k element offset

    for (int k0 = 0; k0 < K; k0 += 32) {
        #pragma unroll
        for (int i = 0; i < 2; ++i) {
            const int c = wave * 2 + i;
            const unsigned short* ga = A + (size_t)(gm0 + c * 16 + srow) * K + (k0 + skoff);
            const unsigned short* gb = W + (size_t)(gn0 + c * 16 + srow) * K + (k0 + skoff);
            __builtin_amdgcn_global_load_lds(
                (const __attribute__((address_space(1))) void*)ga,
                (__attribute__((address_space(3))) void*)((char*)As + c * 1024), 16, 0, 0);
            __builtin_amdgcn_global_load_lds(
                (const __attribute__((address_space(1))) void*)gb,
                (__attribute__((address_space(3))) void*)((char*)Bs + c * 1024), 16, 0, 0);
        }
        __syncthreads();
        bf16x8 af[4], bfr[4];
        #pragma unroll
        for (int m = 0; m < 4; ++m)
            af[m] = *(const bf16x8*)&As[(wr * 64 + m * 16 + (lane & 15)) * 32 + (lane >> 4) * 8];
        #pragma unroll
        for (int n = 0; n < 4; ++n)
            bfr[n] = *(const bf16x8*)&Bs[(wc * 64 + n * 16 + (lane & 15)) * 32 + (lane >> 4) * 8];
        #pragma unroll
        for (int m = 0; m < 4; ++m)
            #pragma unroll
            for (int n = 0; n < 4; ++n)
                acc[m][n] = __builtin_amdgcn_mfma_f32_16x16x32_bf16(af[m], bfr[n], acc[m][n], 0, 0, 0);
        __syncthreads();
    }

    // epilogue
    #pragma unroll
    for (int m = 0; m < 4; ++m)
    #pragma unroll
    for (int n = 0; n < 4; ++n)
    #pragma unroll
    for (int j = 0; j < 4; ++j) {
        const int r = gm0 + wr * 64 + m * 16 + (lane >> 4) * 4 + j;
        const int c = gn0 + wc * 64 + n * 16 + (lane & 15);
        const float val = acc[m][n][j] + bias[c];
        if constexpr (EPI == 0) {            // qk: mix with Query/Key inputs
            const int bb = r >> 10, nn = r & 1023;
            const int h = c >> 7, hs = (c >> 1) & 63, isk = c & 1;
            const size_t idx = (((size_t)(bb * 16 + h)) * 1024 + nn) * 64 + hs;
            if (!isk) { const float mx = 0.7f * val + 0.3f * e0[idx]; o0[idx] = mx; u0[idx] = f2bf(mx); }
            else      { const float mx = 0.7f * val + 0.3f * e1[idx]; o1[idx] = mx; u1[idx] = f2bf(mx); }
        } else if constexpr (EPI == 1) {     // v: mix + write transposed bf16
            const int bb = r >> 10, nn = r & 1023;
            const int h = c >> 6, hs = c & 63;
            const size_t idx = (((size_t)(bb * 16 + h)) * 1024 + nn) * 64 + hs;
            const float mx = 0.7f * val + 0.3f * e0[idx];
            o0[idx] = mx;
            u0[(((size_t)(bb * 16 + h)) * 64 + hs) * 1024 + nn] = f2bf(mx);
        } else if constexpr (EPI == 2) {     // out-proj + residual -> fp32 y1
            const size_t idx = (size_t)r * N + c;
            o0[idx] = val + e0[idx];
        } else if constexpr (EPI == 3) {     // GELU (exact, erf) -> bf16
            const float g = 0.5f * val * (1.0f + erff(val * 0.70710678118f));
            u0[(size_t)r * N + c] = f2bf(g);
        } else {                             // mlp2 + residual -> fp32 out
            const size_t idx = (size_t)r * N + c;
            o0[idx] = val + e0[idx];
        }
    }
}

// ---------------------------------------------------------------------------
// Flash attention, swapped-QK^T in-register softmax. No LDS, no barriers.
// grid (N/64, B*H), 256 threads = 4 waves x 16 q-rows.
// Qb,Kb: (B*H, N, 64) bf16.  Vt: (B*H, 64, N) bf16.  Ob: (B*N, 1024) bf16.
//
// Layouts (all from the round-0-verified 16x16x32 mappings):
//  S^T = mfma(A=K_frag, B=Q_frag): lane(q=l&15, g=l>>4) holds
//        s[kt][j] = S[q][kb + kt*16 + g*4 + j]        (C layout, swapped)
//  PV A-frag needs lane to hold P[q=l&15][key = 32*Bb + g*8 + i], i=0..7
//    -> built from packed bf16 pairs by an 8-shfl exchange per 32-key block.
//  PV B-frag: V^T rows -> contiguous 16B loads.
//  O accumulates as D[m=q][n=d]: o[dt][j] = O[g*4+j][dt*16 + (l&15)].
// ---------------------------------------------------------------------------
__global__ __launch_bounds__(256, 4)
void attn_kernel(const unsigned short* __restrict__ Qb,
                 const unsigned short* __restrict__ Kb,
                 const unsigned short* __restrict__ Vt,
                 unsigned short* __restrict__ Ob) {
    const int bh = blockIdx.y;
    const int b = bh >> 4, h = bh & 15;
    const int tid = threadIdx.x, wave = tid >> 6, lane = tid & 63;
    const int qbase = blockIdx.x * 64 + wave * 16;
    const int q15 = lane & 15, g = lane >> 4;

    const unsigned short* Qh = Qb + (size_t)bh * 1024 * 64;
    const unsigned short* Kh = Kb + (size_t)bh * 1024 * 64;
    const unsigned short* Vh = Vt + (size_t)bh * 64 * 1024;

    // Q as B-operand fragments: lane holds Q[qbase+q15][kk*32 + g*8 .. +7]
    bf16x8 aq[2];
    aq[0] = *(const bf16x8*)&Qh[(size_t)(qbase + q15) * 64 + 0  + g * 8];
    aq[1] = *(const bf16x8*)&Qh[(size_t)(qbase + q15) * 64 + 32 + g * 8];

    f32x4 o[4] = {};
    float mrow = -1e30f, lrow = 0.f;   // softmax state for q-row q15

    for (int t = 0; t < 16; ++t) {
        const int kb = t * 64;
        // ---- QK^T (swapped) ----
        f32x4 s[4] = {};
        #pragma unroll
        for (int kt = 0; kt < 4; ++kt) {
            #pragma unroll
            for (int kk = 0; kk < 2; ++kk) {
                bf16x8 bk = *(const bf16x8*)&Kh[(size_t)(kb + kt * 16 + q15) * 64 + kk * 32 + g * 8];
                s[kt] = __builtin_amdgcn_mfma_f32_16x16x32_bf16(bk, aq[kk], s[kt], 0, 0, 0);
            }
        }
        // ---- online softmax (row = q15, lane-local) ----
        float pm = -1e30f;
        #pragma unroll
        for (int kt = 0; kt < 4; ++kt) {
            s[kt] *= 0.125f;   // 1/sqrt(64)
            pm = fmaxf(pm, fmaxf(fmaxf(s[kt][0], s[kt][1]), fmaxf(s[kt][2], s[kt][3])));
        }
        pm = fmaxf(pm, __shfl_xor(pm, 16, 64));
        pm = fmaxf(pm, __shfl_xor(pm, 32, 64));
        const float mnew = fmaxf(mrow, pm);
        const float alpha = __expf(mrow - mnew);
        mrow = mnew;

        float rs = 0.f;
        unsigned int pk0[4], pk1[4];
        #pragma unroll
        for (int kt = 0; kt < 4; ++kt) {
            const float p0 = __expf(s[kt][0] - mnew);
            const float p1 = __expf(s[kt][1] - mnew);
            const float p2 = __expf(s[kt][2] - mnew);
            const float p3 = __expf(s[kt][3] - mnew);
            rs += (p0 + p1) + (p2 + p3);
            pk0[kt] = (unsigned int)f2bf(p0) | ((unsigned int)f2bf(p1) << 16);
            pk1[kt] = (unsigned int)f2bf(p2) | ((unsigned int)f2bf(p3) << 16);
        }
        rs += __shfl_xor(rs, 16, 64);
        rs += __shfl_xor(rs, 32, 64);
        lrow = lrow * alpha + rs;

        // rescale O: row j of o belongs to q-row (g*4+j); its alpha lives at lane (g*4+j)
        float af[4];
        #pragma unroll
        for (int j = 0; j < 4; ++j) af[j] = __shfl(alpha, g * 4 + j, 64);
        #pragma unroll
        for (int dt = 0; dt < 4; ++dt)
            #pragma unroll
            for (int j = 0; j < 4; ++j) o[dt][j] *= af[j];

        // ---- exchange P into A-fragments, PV ----
        const int src0 = q15 + ((lane & 16) << 1);   // q15 + 32*(g&1)
        const int src1 = src0 + 16;
        const bool hi = (g >> 1) != 0;
        #pragma unroll
        for (int Bb = 0; Bb < 2; ++Bb) {
            const unsigned int a0 = (unsigned int)__shfl((int)pk0[2 * Bb],     src0, 64);
            const unsigned int a1 = (unsigned int)__shfl((int)pk0[2 * Bb + 1], src0, 64);
            const unsigned int b0 = (unsigned int)__shfl((int)pk1[2 * Bb],     src0, 64);
            const unsigned int b1 = (unsigned int)__shfl((int)pk1[2 * Bb + 1], src0, 64);
            const unsigned int c0 = (unsigned int)__shfl((int)pk0[2 * Bb],     src1, 64);
            const unsigned int c1 = (unsigned int)__shfl((int)pk0[2 * Bb + 1], src1, 64);
            const unsigned int d0 = (unsigned int)__shfl((int)pk1[2 * Bb],     src1, 64);
            const unsigned int d1 = (unsigned int)__shfl((int)pk1[2 * Bb + 1], src1, 64);
            union { unsigned int u[4]; bf16x8 v; } pw;
            pw.u[0] = hi ? a1 : a0;
            pw.u[1] = hi ? b1 : b0;
            pw.u[2] = hi ? c1 : c0;
            pw.u[3] = hi ? d1 : d0;
            #pragma unroll
            for (int dt = 0; dt < 4; ++dt) {
                bf16x8 vb = *(const bf16x8*)&Vh[(size_t)(dt * 16 + q15) * 1024 + kb + Bb * 32 + g * 8];
                o[dt] = __builtin_amdgcn_mfma_f32_16x16x32_bf16(pw.v, vb, o[dt], 0, 0, 0);
            }
        }
    }

    // ---- epilogue: divide by row sum (lives at lane g*4+j), store ----
    float lf[4];
    #pragma unroll
    for (int j = 0; j < 4; ++j) lf[j] = __shfl(lrow, g * 4 + j, 64);
    #pragma unroll
    for (int dt = 0; dt < 4; ++dt)
        #pragma unroll
        for (int j = 0; j < 4; ++j) {
            const int q = qbase + g * 4 + j;
            Ob[((size_t)(b * 1024 + q)) * 1024 + h * 64 + dt * 16 + q15] = f2bf(o[dt][j] / lf[j]);
        }
}

// ---------------------------------------------------------------------------
// Launch
// ---------------------------------------------------------------------------
extern "C" void kernel_launch(void* const* d_in, const int* in_sizes, int n_in,
                              void* d_out, int out_size, void* d_ws, size_t ws_size,
                              hipStream_t stream) {
    (void)in_sizes; (void)n_in; (void)out_size; (void)ws_size;
    const float* x     = (const float*)d_in[0];
    const float* Qin   = (const float*)d_in[1];
    const float* Kin   = (const float*)d_in[2];
    const float* Vin   = (const float*)d_in[3];
    const float* ln_w  = (const float*)d_in[4];
    const float* ln_b  = (const float*)d_in[5];
    const float* qk_w  = (const float*)d_in[6];
    const float* qk_b  = (const float*)d_in[7];
    const float* v_w   = (const float*)d_in[8];
    const float* v_b   = (const float*)d_in[9];
    const float* out_w = (const float*)d_in[10];
    const float* out_b = (const float*)d_in[11];
    const float* w1    = (const float*)d_in[12];
    const float* b1    = (const float*)d_in[13];
    const float* w2    = (const float*)d_in[14];
    const float* b2    = (const float*)d_in[15];

    const size_t FOUR_M = (size_t)4 * 1024 * 1024;
    float* out0 = (float*)d_out;
    float* Qout = out0 + FOUR_M;
    float* Kout = Qout + FOUR_M;
    float* Vout = Kout + FOUR_M;

    char* ws = (char*)d_ws;
    const size_t MB = 1024 * 1024;
    unsigned short* xn   = (unsigned short*)(ws + 0);        // 8MB (reused as xn2)
    unsigned short* qkwb = (unsigned short*)(ws + 8 * MB);   // 4MB
    unsigned short* vwb  = (unsigned short*)(ws + 12 * MB);  // 2MB
    unsigned short* owb  = (unsigned short*)(ws + 14 * MB);  // 2MB
    unsigned short* w1b  = (unsigned short*)(ws + 16 * MB);  // 8MB
    unsigned short* w2b  = (unsigned short*)(ws + 24 * MB);  // 8MB
    unsigned short* Qbuf = (unsigned short*)(ws + 32 * MB);  // 8MB
    unsigned short* Kbuf = (unsigned short*)(ws + 40 * MB);  // 8MB
    unsigned short* Vtb  = (unsigned short*)(ws + 48 * MB);  // 8MB
    unsigned short* atto = (unsigned short*)(ws + 56 * MB);  // 8MB
    unsigned short* hbuf = (unsigned short*)(ws + 32 * MB);  // 32MB, reuses Q/K/V/atto region
    float* y1 = (float*)(ws + 64 * MB);                      // 16MB

    // weight converts
    cvt_kernel<<<2048, 256, 0, stream>>>(qk_w, qkwb, 2048 * 1024);
    cvt_kernel<<<1024, 256, 0, stream>>>(v_w,  vwb,  1024 * 1024);
    cvt_kernel<<<1024, 256, 0, stream>>>(out_w, owb, 1024 * 1024);
    cvt_kernel<<<4096, 256, 0, stream>>>(w1, w1b, 4096 * 1024);
    cvt_kernel<<<4096, 256, 0, stream>>>(w2, w2b, 4096 * 1024);

    // LN1
    ln_kernel<<<4096, 256, 0, stream>>>(x, ln_w, ln_b, xn);

    // qk projection + mixing
    {
        dim3 g(2048 / 128, 4096 / 128);
        gemm_bt<0><<<g, 256, 0, stream>>>(xn, qkwb, qk_b, 4096, 2048, 1024,
                                          Qin, Kin, Qout, Kout, Qbuf, Kbuf);
    }
    // v projection + mixing (+ transposed bf16 copy)
    {
        dim3 g(1024 / 128, 4096 / 128);
        gemm_bt<1><<<g, 256, 0, stream>>>(xn, vwb, v_b, 4096, 1024, 1024,
                                          Vin, nullptr, Vout, nullptr, Vtb, nullptr);
    }
    // attention
    {
        dim3 g(16, 64);
        attn_kernel<<<g, 256, 0, stream>>>(Qbuf, Kbuf, Vtb, atto);
    }
    // out projection + residual -> y1
    {
        dim3 g(1024 / 128, 4096 / 128);
        gemm_bt<2><<<g, 256, 0, stream>>>(atto, owb, out_b, 4096, 1024, 1024,
                                          x, nullptr, y1, nullptr, nullptr, nullptr);
    }
    // LN2
    ln_kernel<<<4096, 256, 0, stream>>>(y1, ln_w, ln_b, xn);
    // MLP fc1 + GELU
    {
        dim3 g(4096 / 128, 4096 / 128);
        gemm_bt<3><<<g, 256, 0, stream>>>(xn, w1b, b1, 4096, 4096, 1024,
                                          nullptr, nullptr, nullptr, nullptr, hbuf, nullptr);
    }
    // MLP fc2 + residual -> out0
    {
        dim3 g(1024 / 128, 4096 / 128);
        gemm_bt<4><<<g, 256, 0, stream>>>(hbuf, w2b, b2, 4096, 1024, 4096,
                                          y1, nullptr, out0, nullptr, nullptr, nullptr);
    }
}